// Round 5
// baseline (69.406 us; speedup 1.0000x reference)
//
#include <hip/hip_runtime.h>
#include <float.h>

// Problem constants (from reference)
#define NBX 512
#define NBY 512
#define NBINS (NBX * NBY)

// Region decomposition: 32x32 regions of 16x16 bins each.
#define NREG 1024
#define TILE_W 18                     // 16 + 2 halo cells per axis
#define TILE_ELEMS (TILE_W * TILE_W)  // 324

// v5 packed accumulator: u64 words of 6 x 10-bit fields = 2 columns x 3 rows.
// Two x-phase grids: phase p pair j covers columns (2j+p, 2j+p+1).
// A node's 3x3 patch (cols colb..colb+2, rows k..k+2):
//   wordA = pair (p=colb&1, j=colb>>1)      -> cols colb, colb+1 (6 fields)
//   wordB = pair (p, j+1)                   -> col  colb+2       (3 fields)
// k-window index = k (16 windows, rows k..k+2 up to 17).
#define PAIRS 9
#define KWIN 16
#define TPW (2 * PAIRS * KWIN)   // 288 u64 = 2304 B
#define QSCALE 128.0f
#define INV_QSCALE (1.0f / 128.0f)

#define CHUNK 8192
#define CBLK 256
#define RBLOCKS 256
#define RTHREADS 256

// node sizes in [0.2,1.0] => stretched half-widths sx=sy=1.0 exactly,
// scale = 0.25*nsx*nsy, and each axis stencil = 3 bins with analytic
// weights (1-f, 1, f), f = c-1-floor(c-1).

__device__ __forceinline__ int node_region(const float* __restrict__ pos,
                                           const float* __restrict__ nsx_,
                                           const float* __restrict__ nsy_,
                                           int i, int n,
                                           float& cx, float& cy, float& sc) {
    float x = pos[i];
    float y = pos[i + n];
    float nx = nsx_[i];
    float ny = nsy_[i];
    cx = x + 0.5f * nx;
    cy = y + 0.5f * ny;
    sc = 0.25f * nx * ny;
    int bx0 = (int)floorf(cx - 1.0f);
    int by0 = (int)floorf(cy - 1.0f);
    int rgx = min(max(bx0, 0), NBX - 1) >> 4;
    int rgy = min(max(by0, 0), NBY - 1) >> 4;
    return (rgx << 5) | rgy;
}

// K1: per-chunk region histogram (LDS u32 atomics)
__global__ void count_kernel(const float* __restrict__ pos,
                             const float* __restrict__ nsx_,
                             const float* __restrict__ nsy_,
                             int* __restrict__ cnt, int n) {
    __shared__ int lhist[NREG];
    int b = blockIdx.x, tid = threadIdx.x;
    for (int r = tid; r < NREG; r += CBLK) lhist[r] = 0;
    __syncthreads();
    int start = b * CHUNK;
    for (int it = 0; it < CHUNK / CBLK; ++it) {
        int i = start + it * CBLK + tid;
        if (i < n) {
            float cx, cy, sc;
            int r = node_region(pos, nsx_, nsy_, i, n, cx, cy, sc);
            atomicAdd(&lhist[r], 1);
        }
    }
    __syncthreads();
    for (int r = tid; r < NREG; r += CBLK) cnt[b * NREG + r] = lhist[r];
}

// K2: per-region exclusive scan over chunks (one wave per region)
__global__ void scan_chunks_kernel(const int* __restrict__ cnt,
                                   int* __restrict__ rowoff,
                                   int* __restrict__ totals, int nchunk) {
    int r = blockIdx.x;
    int lane = threadIdx.x;  // 0..63
    int running = 0;
    for (int seg = 0; seg < nchunk; seg += 64) {
        int b = seg + lane;
        int c = (b < nchunk) ? cnt[b * NREG + r] : 0;
        int inc = c;
        for (int d = 1; d < 64; d <<= 1) {
            int v = __shfl_up(inc, d, 64);
            if (lane >= d) inc += v;
        }
        if (b < nchunk) rowoff[b * NREG + r] = running + (inc - c);
        running += __shfl(inc, 63, 64);
    }
    if (lane == 0) totals[r] = running;
}

// K3: exclusive scan of 1024 region totals
__global__ void scan_totals_kernel(const int* __restrict__ totals,
                                   int* __restrict__ base) {
    __shared__ int buf[NREG];
    int t = threadIdx.x;
    int my = totals[t];
    buf[t] = my;
    __syncthreads();
    for (int d = 1; d < NREG; d <<= 1) {
        int v = (t >= d) ? buf[t - d] : 0;
        __syncthreads();
        buf[t] += v;
        __syncthreads();
    }
    base[t] = buf[t] - my;  // exclusive
}

// K4: region-sorted payload scatter (float4 payload, LDS cursors)
__global__ void scatter_sort_kernel(const float* __restrict__ pos,
                                    const float* __restrict__ nsx_,
                                    const float* __restrict__ nsy_,
                                    const int* __restrict__ base,
                                    const int* __restrict__ rowoff,
                                    float4* __restrict__ payload, int n) {
    __shared__ int lcur[NREG];
    int b = blockIdx.x, tid = threadIdx.x;
    for (int r = tid; r < NREG; r += CBLK)
        lcur[r] = base[r] + rowoff[b * NREG + r];
    __syncthreads();
    int start = b * CHUNK;
    for (int it = 0; it < CHUNK / CBLK; ++it) {
        int i = start + it * CBLK + tid;
        if (i < n) {
            float cx, cy, sc;
            int r = node_region(pos, nsx_, nsy_, i, n, cx, cy, sc);
            int p = atomicAdd(&lcur[r], 1);
            payload[p] = make_float4(cx, cy, sc, 0.0f);
        }
    }
}

// K5: per-region accumulation, ~2 packed u64 LDS atomics per node.
__global__ void accumulate_packed_kernel(const float4* __restrict__ payload,
                                         const int* __restrict__ base,
                                         const int* __restrict__ totals,
                                         float* __restrict__ tiles) {
    __shared__ unsigned long long tp[TPW];
    int r = blockIdx.x, tid = threadIdx.x;
    for (int j = tid; j < TPW; j += 256) tp[j] = 0ull;
    __syncthreads();
    int s = base[r];
    int e = s + totals[r];
    int ox = (r >> 5) << 4;
    int oy = (r & 31) << 4;
    for (int i = s + tid; i < e; i += 256) {
        float4 p = payload[i];
        float cx = p.x, cy = p.y, sc = p.z;
        float bx0f = floorf(cx - 1.0f);
        float by0f = floorf(cy - 1.0f);
        int bx0 = (int)bx0f;
        int by0 = (int)by0f;
        float fx = cx - 1.0f - bx0f;  // in [0,1)
        float fy = cy - 1.0f - by0f;
        float wx0 = 1.0f - fx, wx1 = 1.0f, wx2 = fx;
        float wy0 = 1.0f - fy, wy1 = 1.0f, wy2 = fy;
        if (bx0 < 0) { bx0 = 0; wx0 = 1.0f; wx1 = fx; wx2 = 0.0f; }
        if (bx0 >= NBX - 2) wx2 = 0.0f;   // drop column at bin 512
        if (by0 < 0) { by0 = 0; wy0 = 1.0f; wy1 = fy; wy2 = 0.0f; }
        if (by0 >= NBY - 2) wy2 = 0.0f;   // drop row at bin 512

        int colb = bx0 - ox;         // 0..15
        int k = by0 - oy;            // 0..15
        int pph = colb & 1;
        int jp = colb >> 1;          // wordA pair; wordB pair = jp+1 (<= 8)

        float q0f = sc * wy0 * QSCALE;
        float q1f = sc * wy1 * QSCALE;
        float q2f = sc * wy2 * QSCALE;

        unsigned long long a0 = (unsigned int)(q0f * wx0 + 0.5f);
        unsigned long long a1 = (unsigned int)(q1f * wx0 + 0.5f);
        unsigned long long a2 = (unsigned int)(q2f * wx0 + 0.5f);
        unsigned long long b0 = (unsigned int)(q0f * wx1 + 0.5f);
        unsigned long long b1 = (unsigned int)(q1f * wx1 + 0.5f);
        unsigned long long b2 = (unsigned int)(q2f * wx1 + 0.5f);
        unsigned long long c0 = (unsigned int)(q0f * wx2 + 0.5f);
        unsigned long long c1 = (unsigned int)(q1f * wx2 + 0.5f);
        unsigned long long c2 = (unsigned int)(q2f * wx2 + 0.5f);

        int baseIdx = (pph * PAIRS + jp) * KWIN + k;
        unsigned long long wA = a0 | (a1 << 10) | (a2 << 20) |
                                (b0 << 30) | (b1 << 40) | (b2 << 50);
        atomicAdd(&tp[baseIdx], wA);
        unsigned long long wB = c0 | (c1 << 10) | (c2 << 20);
        if (wB) atomicAdd(&tp[baseIdx + KWIN], wB);
    }
    __syncthreads();
    // Unpack: cell (col,y) sums <=2 phases x <=3 k-windows.
    for (int c = tid; c < TILE_ELEMS; c += 256) {
        int col = c / TILE_W;
        int y = c - col * TILE_W;
        unsigned int acc = 0;
#pragma unroll
        for (int p = 0; p < 2; ++p) {
            int t = col - p;
            if (t < 0) continue;
            int sub = t & 1;
            int j = t >> 1;
            if (j >= PAIRS) continue;
#pragma unroll
            for (int rdy = 0; rdy < 3; ++rdy) {
                int kk = y - rdy;
                if (kk < 0 || kk >= KWIN) continue;
                unsigned long long w = tp[(p * PAIRS + j) * KWIN + kk];
                acc += (unsigned int)(w >> ((sub * 3 + rdy) * 10)) & 0x3FFu;
            }
        }
        tiles[r * TILE_ELEMS + c] = (float)acc * INV_QSCALE;
    }
}

// K6: gather (<=4 tiles per bin) + init map, fused overflow/max partial reduce
__global__ void gather_reduce_kernel(const float* __restrict__ tiles,
                                     const float* __restrict__ init_map,
                                     float* __restrict__ psum,
                                     float* __restrict__ pmax) {
    __shared__ float ssum[RTHREADS];
    __shared__ float smax[RTHREADS];
    float s = 0.0f;
    float m = -FLT_MAX;
    for (int i = blockIdx.x * blockDim.x + threadIdx.x; i < NBINS;
         i += gridDim.x * blockDim.x) {
        int gx = i >> 9;
        int gy = i & (NBY - 1);
        float v = init_map[i];
        int rx1 = gx >> 4, ry1 = gy >> 4;
#pragma unroll
        for (int dx = 0; dx < 2; ++dx) {
            int rx = rx1 - dx;
            if (rx < 0) continue;
            int tix = gx - rx * 16;
            if (tix >= TILE_W) continue;
#pragma unroll
            for (int dy = 0; dy < 2; ++dy) {
                int ry = ry1 - dy;
                if (ry < 0) continue;
                int tiy = gy - ry * 16;
                if (tiy >= TILE_W) continue;
                v += tiles[((rx << 5) | ry) * TILE_ELEMS + tix * TILE_W + tiy];
            }
        }
        s += fmaxf(v - 1.0f, 0.0f);
        m = fmaxf(m, v);
    }
    ssum[threadIdx.x] = s;
    smax[threadIdx.x] = m;
    __syncthreads();
    for (int off = RTHREADS / 2; off > 0; off >>= 1) {
        if (threadIdx.x < off) {
            ssum[threadIdx.x] += ssum[threadIdx.x + off];
            smax[threadIdx.x] = fmaxf(smax[threadIdx.x], smax[threadIdx.x + off]);
        }
        __syncthreads();
    }
    if (threadIdx.x == 0) {
        psum[blockIdx.x] = ssum[0];
        pmax[blockIdx.x] = smax[0];
    }
}

__global__ void final_reduce_kernel(const float* __restrict__ psum,
                                    const float* __restrict__ pmax,
                                    float* __restrict__ out) {
    __shared__ float ssum[RBLOCKS];
    __shared__ float smax[RBLOCKS];
    int t = threadIdx.x;
    ssum[t] = psum[t];
    smax[t] = pmax[t];
    __syncthreads();
    for (int off = RBLOCKS / 2; off > 0; off >>= 1) {
        if (t < off) {
            ssum[t] += ssum[t + off];
            smax[t] = fmaxf(smax[t], smax[t + off]);
        }
        __syncthreads();
    }
    if (t == 0) {
        out[0] = ssum[0];
        out[1] = smax[0];
    }
}

// ---------- fallback path (direct global atomics), used if ws too small ----
__global__ void init_map_kernel(const float* __restrict__ init_map,
                                float* __restrict__ dm, int nbins) {
    int i = blockIdx.x * blockDim.x + threadIdx.x;
    if (i < nbins) dm[i] = init_map[i];
}

__global__ void scatter_direct_kernel(const float* __restrict__ pos,
                                      const float* __restrict__ ns_x,
                                      const float* __restrict__ ns_y,
                                      float* __restrict__ dm, int n_nodes) {
    int i = blockIdx.x * blockDim.x + threadIdx.x;
    if (i >= n_nodes) return;
    float cx, cy, sc;
    node_region(pos, ns_x, ns_y, i, n_nodes, cx, cy, sc);
    int bx0 = (int)floorf(cx - 1.0f);
    int by0 = (int)floorf(cy - 1.0f);
#pragma unroll
    for (int kx = 0; kx < 3; ++kx) {
        int bix = bx0 + kx;
        if (bix < 0 || bix >= NBX) continue;
        float bl = (float)bix;
        float ox = fmaxf(fminf(cx + 1.0f, bl + 1.0f) - fmaxf(cx - 1.0f, bl), 0.0f);
        float sox = sc * ox;
#pragma unroll
        for (int ky = 0; ky < 3; ++ky) {
            int biy = by0 + ky;
            if (biy < 0 || biy >= NBY) continue;
            bl = (float)biy;
            float oy = fmaxf(fminf(cy + 1.0f, bl + 1.0f) - fmaxf(cy - 1.0f, bl), 0.0f);
            atomicAdd(&dm[bix * NBY + biy], sox * oy);
        }
    }
}

__global__ void reduce_dm_kernel(const float* __restrict__ dm,
                                 float* __restrict__ psum,
                                 float* __restrict__ pmax, int nbins) {
    __shared__ float ssum[RTHREADS];
    __shared__ float smax[RTHREADS];
    float s = 0.0f;
    float m = -FLT_MAX;
    for (int i = blockIdx.x * blockDim.x + threadIdx.x; i < nbins;
         i += gridDim.x * blockDim.x) {
        float v = dm[i];
        s += fmaxf(v - 1.0f, 0.0f);
        m = fmaxf(m, v);
    }
    ssum[threadIdx.x] = s;
    smax[threadIdx.x] = m;
    __syncthreads();
    for (int off = RTHREADS / 2; off > 0; off >>= 1) {
        if (threadIdx.x < off) {
            ssum[threadIdx.x] += ssum[threadIdx.x + off];
            smax[threadIdx.x] = fmaxf(smax[threadIdx.x], smax[threadIdx.x + off]);
        }
        __syncthreads();
    }
    if (threadIdx.x == 0) {
        psum[blockIdx.x] = ssum[0];
        pmax[blockIdx.x] = smax[0];
    }
}
// ---------------------------------------------------------------------------

extern "C" void kernel_launch(void* const* d_in, const int* in_sizes, int n_in,
                              void* d_out, int out_size, void* d_ws, size_t ws_size,
                              hipStream_t stream) {
    const float* pos = (const float*)d_in[0];
    const float* ns_x = (const float*)d_in[1];
    const float* ns_y = (const float*)d_in[2];
    const float* init_map = (const float*)d_in[3];
    float* out = (float*)d_out;

    int n = in_sizes[1];  // node count
    int nchunk = (n + CHUNK - 1) / CHUNK;
    char* ws = (char*)d_ws;

    size_t off = 0;
    auto alloc = [&](size_t bytes) {
        size_t cur = off;
        off += (bytes + 255) & ~(size_t)255;
        return cur;
    };
    size_t o_payload = alloc((size_t)n * 16);
    size_t o_cnt = alloc((size_t)nchunk * NREG * 4);
    size_t o_rowoff = alloc((size_t)nchunk * NREG * 4);
    size_t o_totals = alloc(NREG * 4);
    size_t o_base = alloc(NREG * 4);
    size_t o_tiles = alloc((size_t)NREG * TILE_ELEMS * 4);
    size_t o_psum = alloc(RBLOCKS * 4);
    size_t o_pmax = alloc(RBLOCKS * 4);

    if (ws_size >= off) {
        float4* payload = (float4*)(ws + o_payload);
        int* cnt = (int*)(ws + o_cnt);
        int* rowoff = (int*)(ws + o_rowoff);
        int* totals = (int*)(ws + o_totals);
        int* base = (int*)(ws + o_base);
        float* tiles = (float*)(ws + o_tiles);
        float* psum = (float*)(ws + o_psum);
        float* pmax = (float*)(ws + o_pmax);

        count_kernel<<<nchunk, CBLK, 0, stream>>>(pos, ns_x, ns_y, cnt, n);
        scan_chunks_kernel<<<NREG, 64, 0, stream>>>(cnt, rowoff, totals, nchunk);
        scan_totals_kernel<<<1, NREG, 0, stream>>>(totals, base);
        scatter_sort_kernel<<<nchunk, CBLK, 0, stream>>>(pos, ns_x, ns_y, base,
                                                         rowoff, payload, n);
        accumulate_packed_kernel<<<NREG, 256, 0, stream>>>(payload, base, totals, tiles);
        gather_reduce_kernel<<<RBLOCKS, RTHREADS, 0, stream>>>(tiles, init_map,
                                                               psum, pmax);
        final_reduce_kernel<<<1, RBLOCKS, 0, stream>>>(psum, pmax, out);
    } else {
        float* dm = (float*)d_ws;
        float* psum = dm + NBINS;
        float* pmax = psum + RBLOCKS;
        init_map_kernel<<<(NBINS + 255) / 256, 256, 0, stream>>>(init_map, dm, NBINS);
        scatter_direct_kernel<<<(n + 255) / 256, 256, 0, stream>>>(pos, ns_x, ns_y, dm, n);
        reduce_dm_kernel<<<RBLOCKS, RTHREADS, 0, stream>>>(dm, psum, pmax, NBINS);
        final_reduce_kernel<<<1, RBLOCKS, 0, stream>>>(psum, pmax, out);
    }
}

// Round 6
// 59.700 us; speedup vs baseline: 1.1626x; 1.1626x over previous
//
#include <hip/hip_runtime.h>
#include <float.h>

// Problem constants (from reference)
#define NBX 512
#define NBY 512
#define NBINS (NBX * NBY)

// Region decomposition: 32x32 regions of 16x16 bins each.
#define NREG 1024
#define TILE_W 18                     // 16 + 2 halo cells per axis
#define TILE_ELEMS (TILE_W * TILE_W)  // 324

// Packed-tile accumulator (v4 scheme, proven absmax 0): two overlapping u64
// grids of 4x16-bit fields; any 3-consecutive-row triple fits one u64.
#define NGRP 4
#define TP_WORDS (2 * TILE_W * NGRP)  // 144 u64
#define FSCALE 1024.0f
#define INV_FSCALE (1.0f / 1024.0f)

#define CHUNK 8192
#define SBLK 512
#define CAP 2816                 // slots per region (mean ~1953, 13 sigma margin)
#define SPILL_MAX 65536

// Payload: 8B packed node.
// bits 63..55 bx0p(9) = raw bx0+1 (0 => left-clamped, 511 => right edge)
// bits 54..46 by0p(9)
// bits 45..35 fxq(11), 34..24 fyq(11)  (x4: frac * 2047)
// bits 23..0  scq(24) = sc * 2^25  (sc <= 0.25 -> <= 2^23)
//
// node sizes in [0.2,1.0] => stretched half-widths sx=sy=1.0 exactly,
// scale = 0.25*nsx*nsy; axis stencil = 3 bins, weights (1-f,1,f) interior,
// (1,f,0) at left clamp, (1-f,1,0) at right edge.

struct Hdr {
    unsigned int spill_cnt;
    unsigned int done;
    unsigned long long sum_q;
    unsigned int max_bits;
    unsigned int pad;
};

__device__ __forceinline__ unsigned long long pack_node(float x, float y,
                                                        float nx, float ny,
                                                        int& key) {
    float cx = x + 0.5f * nx;
    float cy = y + 0.5f * ny;
    float sc = 0.25f * nx * ny;
    float bx0f = floorf(cx - 1.0f);
    float by0f = floorf(cy - 1.0f);
    int bx0 = (int)bx0f;           // in [-1, 510]
    int by0 = (int)by0f;
    float fx = cx - 1.0f - bx0f;   // [0,1)
    float fy = cy - 1.0f - by0f;
    int bx0p = bx0 + 1;            // [0, 511]
    int by0p = by0 + 1;
    int cbx0 = bx0 < 0 ? 0 : bx0;
    int cby0 = by0 < 0 ? 0 : by0;
    key = ((cbx0 >> 4) << 5) | (cby0 >> 4);
    unsigned int fxq = (unsigned int)(fx * 2047.0f + 0.5f);
    unsigned int fyq = (unsigned int)(fy * 2047.0f + 0.5f);
    unsigned int scq = (unsigned int)(sc * 33554432.0f + 0.5f);
    return ((unsigned long long)bx0p << 55) | ((unsigned long long)by0p << 46) |
           ((unsigned long long)fxq << 35) | ((unsigned long long)fyq << 24) |
           (unsigned long long)scq;
}

// K1: fused histogram + global reservation + placement (one input read).
__global__ __launch_bounds__(SBLK) void scatter_res_kernel(
    const float* __restrict__ pos, const float* __restrict__ nsx_,
    const float* __restrict__ nsy_, unsigned int* __restrict__ cursors,
    unsigned long long* __restrict__ payload,
    unsigned long long* __restrict__ spill, Hdr* __restrict__ hdr, int n) {
    __shared__ unsigned int hist[NREG];                // 4 KB
    __shared__ unsigned long long stage[CHUNK];        // 64 KB
    int b = blockIdx.x, tid = threadIdx.x;
    for (int i = tid; i < NREG; i += SBLK) hist[i] = 0;
    __syncthreads();
    int start = b * CHUNK;
    int cnt = min(CHUNK, n - start);
    for (int j = tid; j < cnt; j += SBLK) {
        int i = start + j;
        int key;
        unsigned long long w = pack_node(pos[i], pos[i + n], nsx_[i], nsy_[i], key);
        stage[j] = w;
        atomicAdd(&hist[key], 1u);
    }
    __syncthreads();
    // Reserve contiguous slots per region; hist[k] becomes the running cursor.
    for (int k = tid; k < NREG; k += SBLK) {
        unsigned int c = hist[k];
        hist[k] = c ? atomicAdd(&cursors[k], c) : 0u;
    }
    __syncthreads();
    for (int j = tid; j < cnt; j += SBLK) {
        unsigned long long w = stage[j];
        int bx0p = (int)(w >> 55);
        int by0p = (int)((w >> 46) & 511u);
        int cbx0 = bx0p > 0 ? bx0p - 1 : 0;
        int cby0 = by0p > 0 ? by0p - 1 : 0;
        int key = ((cbx0 >> 4) << 5) | (cby0 >> 4);
        unsigned int slot = atomicAdd(&hist[key], 1u);
        if (slot < CAP) {
            payload[(size_t)key * CAP + slot] = w;
        } else {
            unsigned int s = atomicAdd(&hdr->spill_cnt, 1u);
            if (s < SPILL_MAX) spill[s] = w;
        }
    }
}

__device__ __forceinline__ void decode_accum(unsigned long long w, int ox, int oy,
                                             unsigned long long* tp) {
    int bx0p = (int)(w >> 55);
    int by0p = (int)((w >> 46) & 511u);
    float fx = (float)((w >> 35) & 2047u) * (1.0f / 2047.0f);
    float fy = (float)((w >> 24) & 2047u) * (1.0f / 2047.0f);
    float sc = (float)(unsigned int)(w & 0xFFFFFFu) * (1.0f / 33554432.0f);
    int bx0 = bx0p > 0 ? bx0p - 1 : 0;
    int by0 = by0p > 0 ? by0p - 1 : 0;
    // weights per clamp case
    float wx0 = (bx0p == 0) ? 1.0f : 1.0f - fx;
    float wx1 = (bx0p == 0) ? fx : 1.0f;
    float wx2 = (bx0p == 0 || bx0p == 511) ? 0.0f : fx;
    float wy0 = (by0p == 0) ? 1.0f : 1.0f - fy;
    float wy1 = (by0p == 0) ? fy : 1.0f;
    float wy2 = (by0p == 0 || by0p == 511) ? 0.0f : fy;

    int colb = bx0 - ox;
    int k = by0 - oy;
    int grid = (k >> 1) & 1;
    int k2 = k - (grid << 1);
    int grp = k2 >> 2;
    int shift = (k2 & 1) << 4;
    float a0 = sc * wy0 * FSCALE;
    float a1 = sc * wy1 * FSCALE;
    float a2 = sc * wy2 * FSCALE;
    int idxb = (grid * TILE_W + colb) * NGRP + grp;
    {
        unsigned long long q0 = (unsigned int)(a0 * wx0 + 0.5f);
        unsigned long long q1 = (unsigned int)(a1 * wx0 + 0.5f);
        unsigned long long q2 = (unsigned int)(a2 * wx0 + 0.5f);
        atomicAdd(&tp[idxb], (q0 << shift) | (q1 << (shift + 16)) | (q2 << (shift + 32)));
    }
    {
        unsigned long long q0 = (unsigned int)(a0 * wx1 + 0.5f);
        unsigned long long q1 = (unsigned int)(a1 * wx1 + 0.5f);
        unsigned long long q2 = (unsigned int)(a2 * wx1 + 0.5f);
        atomicAdd(&tp[idxb + NGRP], (q0 << shift) | (q1 << (shift + 16)) | (q2 << (shift + 32)));
    }
    if (wx2 != 0.0f) {
        unsigned long long q0 = (unsigned int)(a0 * wx2 + 0.5f);
        unsigned long long q1 = (unsigned int)(a1 * wx2 + 0.5f);
        unsigned long long q2 = (unsigned int)(a2 * wx2 + 0.5f);
        atomicAdd(&tp[idxb + 2 * NGRP], (q0 << shift) | (q1 << (shift + 16)) | (q2 << (shift + 32)));
    }
}

// K2: per-region accumulation into packed u64 fixed-point LDS words.
__global__ void accumulate_kernel(const unsigned long long* __restrict__ payload,
                                  const unsigned int* __restrict__ cursors,
                                  const unsigned long long* __restrict__ spill,
                                  const Hdr* __restrict__ hdr,
                                  float* __restrict__ tiles) {
    __shared__ unsigned long long tp[TP_WORDS];
    int r = blockIdx.x, tid = threadIdx.x;
    for (int j = tid; j < TP_WORDS; j += 256) tp[j] = 0ull;
    __syncthreads();
    int ox = (r >> 5) << 4;
    int oy = (r & 31) << 4;
    int cnt = (int)min(cursors[r], (unsigned int)CAP);
    const unsigned long long* seg = payload + (size_t)r * CAP;
    for (int i = tid; i < cnt; i += 256) decode_accum(seg[i], ox, oy, tp);
    unsigned int spn = hdr->spill_cnt;
    if (spn) {
        spn = min(spn, (unsigned int)SPILL_MAX);
        for (unsigned int i = tid; i < spn; i += 256) {
            unsigned long long w = spill[i];
            int bx0p = (int)(w >> 55);
            int by0p = (int)((w >> 46) & 511u);
            int cbx0 = bx0p > 0 ? bx0p - 1 : 0;
            int cby0 = by0p > 0 ? by0p - 1 : 0;
            int key = ((cbx0 >> 4) << 5) | (cby0 >> 4);
            if (key == r) decode_accum(w, ox, oy, tp);
        }
    }
    __syncthreads();
    // Unpack both grids: cell y = grid A field y (y<=15) + grid B field y-2 (y>=2)
    for (int c = tid; c < TILE_ELEMS; c += 256) {
        int col = c / TILE_W;
        int y = c - col * TILE_W;
        unsigned int acc = 0;
        if (y <= 15) {
            unsigned long long a = tp[(0 * TILE_W + col) * NGRP + (y >> 2)];
            acc += (unsigned int)(a >> ((y & 3) * 16)) & 0xFFFFu;
        }
        if (y >= 2) {
            int yb = y - 2;
            unsigned long long bv = tp[(1 * TILE_W + col) * NGRP + (yb >> 2)];
            acc += (unsigned int)(bv >> ((yb & 3) * 16)) & 0xFFFFu;
        }
        tiles[r * TILE_ELEMS + c] = (float)acc * INV_FSCALE;
    }
}

// K3: gather (<=4 tiles per bin) + init map + overflow/max, finalize via
// order-independent integer atomics; last block writes out.
#define GBLOCKS 256

__global__ void gather_fin_kernel(const float* __restrict__ tiles,
                                  const float* __restrict__ init_map,
                                  Hdr* __restrict__ hdr,
                                  float* __restrict__ out) {
    __shared__ float ssum[256];
    __shared__ float smax[256];
    float s = 0.0f;
    float m = -FLT_MAX;
    for (int i = blockIdx.x * blockDim.x + threadIdx.x; i < NBINS;
         i += gridDim.x * blockDim.x) {
        int gx = i >> 9;
        int gy = i & (NBY - 1);
        float v = init_map[i];
        int rx1 = gx >> 4, ry1 = gy >> 4;
#pragma unroll
        for (int dx = 0; dx < 2; ++dx) {
            int rx = rx1 - dx;
            if (rx < 0) continue;
            int tix = gx - rx * 16;
            if (tix >= TILE_W) continue;
#pragma unroll
            for (int dy = 0; dy < 2; ++dy) {
                int ry = ry1 - dy;
                if (ry < 0) continue;
                int tiy = gy - ry * 16;
                if (tiy >= TILE_W) continue;
                v += tiles[((rx << 5) | ry) * TILE_ELEMS + tix * TILE_W + tiy];
            }
        }
        s += fmaxf(v - 1.0f, 0.0f);
        m = fmaxf(m, v);
    }
    ssum[threadIdx.x] = s;
    smax[threadIdx.x] = m;
    __syncthreads();
    for (int off = 128; off > 0; off >>= 1) {
        if (threadIdx.x < off) {
            ssum[threadIdx.x] += ssum[threadIdx.x + off];
            smax[threadIdx.x] = fmaxf(smax[threadIdx.x], smax[threadIdx.x + off]);
        }
        __syncthreads();
    }
    if (threadIdx.x == 0) {
        atomicAdd(&hdr->sum_q,
                  (unsigned long long)((double)ssum[0] * 16777216.0 + 0.5));
        atomicMax(&hdr->max_bits, __float_as_uint(fmaxf(smax[0], 0.0f)));
        __threadfence();
        unsigned int old = atomicAdd(&hdr->done, 1u);
        if (old == gridDim.x - 1) {
            unsigned long long sq = atomicAdd(&hdr->sum_q, 0ull);
            unsigned int mb = atomicMax(&hdr->max_bits, 0u);
            out[0] = (float)((double)sq * (1.0 / 16777216.0));
            out[1] = __uint_as_float(mb);
        }
    }
}

// ---------- fallback path (direct global atomics), used if ws too small ----
__global__ void init_map_kernel(const float* __restrict__ init_map,
                                float* __restrict__ dm, int nbins) {
    int i = blockIdx.x * blockDim.x + threadIdx.x;
    if (i < nbins) dm[i] = init_map[i];
}

__global__ void scatter_direct_kernel(const float* __restrict__ pos,
                                      const float* __restrict__ ns_x,
                                      const float* __restrict__ ns_y,
                                      float* __restrict__ dm, int n_nodes) {
    int i = blockIdx.x * blockDim.x + threadIdx.x;
    if (i >= n_nodes) return;
    float cx = pos[i] + 0.5f * ns_x[i];
    float cy = pos[i + n_nodes] + 0.5f * ns_y[i];
    float sc = 0.25f * ns_x[i] * ns_y[i];
    int bx0 = (int)floorf(cx - 1.0f);
    int by0 = (int)floorf(cy - 1.0f);
#pragma unroll
    for (int kx = 0; kx < 3; ++kx) {
        int bix = bx0 + kx;
        if (bix < 0 || bix >= NBX) continue;
        float bl = (float)bix;
        float ox = fmaxf(fminf(cx + 1.0f, bl + 1.0f) - fmaxf(cx - 1.0f, bl), 0.0f);
        float sox = sc * ox;
#pragma unroll
        for (int ky = 0; ky < 3; ++ky) {
            int biy = by0 + ky;
            if (biy < 0 || biy >= NBY) continue;
            bl = (float)biy;
            float oy = fmaxf(fminf(cy + 1.0f, bl + 1.0f) - fmaxf(cy - 1.0f, bl), 0.0f);
            atomicAdd(&dm[bix * NBY + biy], sox * oy);
        }
    }
}

__global__ void reduce_dm_kernel(const float* __restrict__ dm,
                                 float* __restrict__ psum,
                                 float* __restrict__ pmax, int nbins) {
    __shared__ float ssum[256];
    __shared__ float smax[256];
    float s = 0.0f;
    float m = -FLT_MAX;
    for (int i = blockIdx.x * blockDim.x + threadIdx.x; i < nbins;
         i += gridDim.x * blockDim.x) {
        float v = dm[i];
        s += fmaxf(v - 1.0f, 0.0f);
        m = fmaxf(m, v);
    }
    ssum[threadIdx.x] = s;
    smax[threadIdx.x] = m;
    __syncthreads();
    for (int off = 128; off > 0; off >>= 1) {
        if (threadIdx.x < off) {
            ssum[threadIdx.x] += ssum[threadIdx.x + off];
            smax[threadIdx.x] = fmaxf(smax[threadIdx.x], smax[threadIdx.x + off]);
        }
        __syncthreads();
    }
    if (threadIdx.x == 0) {
        psum[blockIdx.x] = ssum[0];
        pmax[blockIdx.x] = smax[0];
    }
}

__global__ void final_reduce_kernel(const float* __restrict__ psum,
                                    const float* __restrict__ pmax,
                                    float* __restrict__ out) {
    __shared__ float ssum[256];
    __shared__ float smax[256];
    int t = threadIdx.x;
    ssum[t] = psum[t];
    smax[t] = pmax[t];
    __syncthreads();
    for (int off = 128; off > 0; off >>= 1) {
        if (t < off) {
            ssum[t] += ssum[t + off];
            smax[t] = fmaxf(smax[t], smax[t + off]);
        }
        __syncthreads();
    }
    if (t == 0) {
        out[0] = ssum[0];
        out[1] = smax[0];
    }
}
// ---------------------------------------------------------------------------

extern "C" void kernel_launch(void* const* d_in, const int* in_sizes, int n_in,
                              void* d_out, int out_size, void* d_ws, size_t ws_size,
                              hipStream_t stream) {
    const float* pos = (const float*)d_in[0];
    const float* ns_x = (const float*)d_in[1];
    const float* ns_y = (const float*)d_in[2];
    const float* init_map = (const float*)d_in[3];
    float* out = (float*)d_out;

    int n = in_sizes[1];  // node count
    int nchunk = (n + CHUNK - 1) / CHUNK;
    char* ws = (char*)d_ws;

    size_t off = 0;
    auto alloc = [&](size_t bytes) {
        size_t cur = off;
        off += (bytes + 255) & ~(size_t)255;
        return cur;
    };
    size_t o_cursors = alloc(NREG * 4);          // 4 KB (memset)
    size_t o_hdr = alloc(sizeof(Hdr));           // (memset)
    size_t o_spill = alloc((size_t)SPILL_MAX * 8);
    size_t o_payload = alloc((size_t)NREG * CAP * 8);
    size_t o_tiles = alloc((size_t)NREG * TILE_ELEMS * 4);

    if (ws_size >= off) {
        unsigned int* cursors = (unsigned int*)(ws + o_cursors);
        Hdr* hdr = (Hdr*)(ws + o_hdr);
        unsigned long long* spill = (unsigned long long*)(ws + o_spill);
        unsigned long long* payload = (unsigned long long*)(ws + o_payload);
        float* tiles = (float*)(ws + o_tiles);

        // zero cursors + header (they are adjacent at the front of ws)
        hipMemsetAsync(ws, 0, o_spill, stream);

        scatter_res_kernel<<<nchunk, SBLK, 0, stream>>>(pos, ns_x, ns_y, cursors,
                                                        payload, spill, hdr, n);
        accumulate_kernel<<<NREG, 256, 0, stream>>>(payload, cursors, spill, hdr,
                                                    tiles);
        gather_fin_kernel<<<GBLOCKS, 256, 0, stream>>>(tiles, init_map, hdr, out);
    } else {
        // Fallback: direct global atomic scatter (~1.06 MB ws)
        float* dm = (float*)d_ws;
        float* psum = dm + NBINS;
        float* pmax = psum + 256;
        init_map_kernel<<<(NBINS + 255) / 256, 256, 0, stream>>>(init_map, dm, NBINS);
        scatter_direct_kernel<<<(n + 255) / 256, 256, 0, stream>>>(pos, ns_x, ns_y,
                                                                   dm, n);
        reduce_dm_kernel<<<256, 256, 0, stream>>>(dm, psum, pmax, NBINS);
        final_reduce_kernel<<<1, 256, 0, stream>>>(psum, pmax, out);
    }
}